// Round 10
// baseline (49.006 us; speedup 1.0000x reference)
//
#include <hip/hip_runtime.h>

// Chamfer distance via MFMA, B=16, N=M=4096, fp32 in/out. Two dispatches:
//   1) fused main: self-pack targets into LDS -> mfma pair-distance ->
//      row-min -> half-combine -> clamp -> block partial sums
//   2) final: 1-block sum of 512 partials -> mean -> out[0]
// d(q,p) = |q|^2 - 2 q.p + |p|^2 inside mfma_f32_32x32x16_bf16 via hi/lo bf16
// splits (k0..k8: Dekker products of (-2q).p; k9,k10: |p|^2; k11,k12: |q|^2).
// R10: R9 structure (4 strips/wave x half-targets, 4 MFMAs per ds_read) but
//      min accumulate via fminf tree (compiler-scheduled, MFMA-hazard-safe)
//      instead of inline-asm v_min3_f32 — bisects R9's correctness failure.

#define BATCH 16
#define NPTS  4096
#define NQ_TOTAL (BATCH * NPTS)   // 65536 per direction

typedef __attribute__((ext_vector_type(8)))  short bf16x8;
typedef __attribute__((ext_vector_type(16))) float f32x16;
typedef __attribute__((ext_vector_type(4)))  unsigned int u32x4;

union FragCast { bf16x8 v; u32x4 u; };

__device__ __forceinline__ unsigned short bf16_rne(float v) {
    unsigned u = __float_as_uint(v);
    u += 0x7FFFu + ((u >> 16) & 1u);          // round-to-nearest-even
    return (unsigned short)(u >> 16);
}
__device__ __forceinline__ float bf16f(unsigned short h) {
    return __uint_as_float(((unsigned)h) << 16);
}

// Build the A-role fragment for one query strip (same encoding as R6/R8).
__device__ __forceinline__ bf16x8 build_af(const float* __restrict__ qpts,
                                           int b, int strip, int c, int g) {
    const int qi = b * NPTS + strip * 32 + c;
    const float qx = qpts[qi * 3 + 0];
    const float qy = qpts[qi * 3 + 1];
    const float qz = qpts[qi * 3 + 2];
    const float mx = -2.0f * qx, my = -2.0f * qy, mz = -2.0f * qz;
    const float Q  = fmaf(qx, qx, fmaf(qy, qy, qz * qz));
    const unsigned short xh = bf16_rne(mx), xl = bf16_rne(mx - bf16f(xh));
    const unsigned short yh = bf16_rne(my), yl = bf16_rne(my - bf16f(yh));
    const unsigned short zh = bf16_rne(mz), zl = bf16_rne(mz - bf16f(zh));
    const unsigned short Qh = bf16_rne(Q),  Ql = bf16_rne(Q - bf16f(Qh));
    const unsigned short one = 0x3F80;
    bf16x8 af;
    if (g == 0) {
        af[0] = (short)xh; af[1] = (short)xh; af[2] = (short)xl; af[3] = (short)yh;
        af[4] = (short)yh; af[5] = (short)yl; af[6] = (short)zh; af[7] = (short)zh;
    } else {
        af[0] = (short)zl; af[1] = (short)one; af[2] = (short)one; af[3] = (short)Qh;
        af[4] = (short)Ql; af[5] = 0;          af[6] = 0;          af[7] = 0;
    }
    return af;
}

__global__ __launch_bounds__(256, 2) void chamfer_fused_kernel(
    const float* __restrict__ xyz1, const float* __restrict__ xyz2,
    float* __restrict__ partials)
{
    // 512 blocks; XCD swizzle (512 % 8 == 0, bijective).
    const int orig = (int)blockIdx.x;
    const int wfid = (orig & 7) * 64 + (orig >> 3);
    const int sg = wfid & 15;          // strip octet: strips [sg*8, sg*8+8)
    const int b  = (wfid >> 4) & 15;   // batch
    const int d  = wfid >> 8;          // direction

    const int tid = (int)threadIdx.x;
    const int wid = tid >> 6;
    const int l   = tid & 63;
    const int c   = l & 31;
    const int g   = l >> 5;
    const int qw  = wid & 1;           // strip quad within the octet
    const int h   = wid >> 1;          // target half (each half = 2048 pts)

    const float* qpts = d ? xyz2 : xyz1;   // queries: set d
    const float* tpts = d ? xyz1 : xyz2;   // targets: set 1-d

    // ---- 4 A-role fragments (strips sg*8 + qw*4 + {0..3}) ----
    const bf16x8 af0 = build_af(qpts, b, sg * 8 + qw * 4 + 0, c, g);
    const bf16x8 af1 = build_af(qpts, b, sg * 8 + qw * 4 + 1, c, g);
    const bf16x8 af2 = build_af(qpts, b, sg * 8 + qw * 4 + 2, c, g);
    const bf16x8 af3 = build_af(qpts, b, sg * 8 + qw * 4 + 3, c, g);

    f32x16 vzero;
    #pragma unroll
    for (int i = 0; i < 16; ++i) vzero[i] = 0.0f;

    f32x16 rm0, rm1, rm2, rm3;
    #pragma unroll
    for (int i = 0; i < 16; ++i) { rm0[i] = 1e30f; rm1[i] = 1e30f; rm2[i] = 1e30f; rm3[i] = 1e30f; }

    // LDS: [half(2)][tile(16)][lane(64)] u32x4 = 32 KiB staged fragments
    __shared__ u32x4 lds[2048];
    __shared__ float lmin[4][128];     // [wave][strip(4) x row(32)]

    const unsigned short one = 0x3F80;
    const float* tptr = tpts + (size_t)b * NPTS * 3;

    for (int p = 0; p < 4; ++p) {      // 4 phases x (512 targets per half)
        __syncthreads();

        // ---- Self-pack: 1024 points (512 per half region) ----
        #pragma unroll
        for (int k = 0; k < 4; ++k) {
            const int pi  = k * 256 + tid;     // 0..1023
            const int h2  = pi >> 9;           // which half region
            const int idx = pi & 511;          // point within region
            const int gp  = h2 * 2048 + p * 512 + idx;   // global point in batch
            const float x = tptr[gp * 3 + 0];
            const float y = tptr[gp * 3 + 1];
            const float z = tptr[gp * 3 + 2];
            const float S = fmaf(x, x, fmaf(y, y, z * z));
            const unsigned short Xh = bf16_rne(x), Xl = bf16_rne(x - bf16f(Xh));
            const unsigned short Yh = bf16_rne(y), Yl = bf16_rne(y - bf16f(Yh));
            const unsigned short Zh = bf16_rne(z), Zl = bf16_rne(z - bf16f(Zh));
            const unsigned short Sh = bf16_rne(S), Sl = bf16_rne(S - bf16f(Sh));
            FragCast f0, f1;
            f0.v[0] = (short)Xh; f0.v[1] = (short)Xl; f0.v[2] = (short)Xh; f0.v[3] = (short)Yh;
            f0.v[4] = (short)Yl; f0.v[5] = (short)Yh; f0.v[6] = (short)Zh; f0.v[7] = (short)Zl;
            f1.v[0] = (short)Zh; f1.v[1] = (short)Sh; f1.v[2] = (short)Sl; f1.v[3] = (short)one;
            f1.v[4] = (short)one; f1.v[5] = 0;        f1.v[6] = 0;         f1.v[7] = 0;
            const int t  = idx >> 5;
            const int c2 = idx & 31;
            lds[h2 * 1024 + t * 64 + c2]      = f0.u;
            lds[h2 * 1024 + t * 64 + 32 + c2] = f1.u;
        }
        __syncthreads();

        // ---- Inner loop: 16 tiles of THIS WAVE'S half; 2 tiles/iter ----
        const int lbase = h * 1024 + l;
        #pragma unroll 2
        for (int t = 0; t < 16; t += 2) {
            FragCast ta, tb;
            ta.u = lds[lbase + (t + 0) * 64];
            tb.u = lds[lbase + (t + 1) * 64];
            // strips 0,1 (cap in-flight at 4 MFMA results)
            f32x16 o0a = __builtin_amdgcn_mfma_f32_32x32x16_bf16(af0, ta.v, vzero, 0, 0, 0);
            f32x16 o0b = __builtin_amdgcn_mfma_f32_32x32x16_bf16(af0, tb.v, vzero, 0, 0, 0);
            f32x16 o1a = __builtin_amdgcn_mfma_f32_32x32x16_bf16(af1, ta.v, vzero, 0, 0, 0);
            f32x16 o1b = __builtin_amdgcn_mfma_f32_32x32x16_bf16(af1, tb.v, vzero, 0, 0, 0);
            #pragma unroll
            for (int i = 0; i < 16; ++i) {
                rm0[i] = fminf(rm0[i], fminf(o0a[i], o0b[i]));   // min3-fusable tree
                rm1[i] = fminf(rm1[i], fminf(o1a[i], o1b[i]));
            }
            // strips 2,3
            f32x16 o2a = __builtin_amdgcn_mfma_f32_32x32x16_bf16(af2, ta.v, vzero, 0, 0, 0);
            f32x16 o2b = __builtin_amdgcn_mfma_f32_32x32x16_bf16(af2, tb.v, vzero, 0, 0, 0);
            f32x16 o3a = __builtin_amdgcn_mfma_f32_32x32x16_bf16(af3, ta.v, vzero, 0, 0, 0);
            f32x16 o3b = __builtin_amdgcn_mfma_f32_32x32x16_bf16(af3, tb.v, vzero, 0, 0, 0);
            #pragma unroll
            for (int i = 0; i < 16; ++i) {
                rm2[i] = fminf(rm2[i], fminf(o2a[i], o2b[i]));
                rm3[i] = fminf(rm3[i], fminf(o3a[i], o3b[i]));
            }
        }
    }

    // ---- Cross-lane min over the 32 columns (within each 32-lane half) ----
    #pragma unroll
    for (int m = 1; m <= 16; m <<= 1) {
        #pragma unroll
        for (int i = 0; i < 16; ++i) {
            rm0[i] = fminf(rm0[i], __shfl_xor(rm0[i], m, 64));
            rm1[i] = fminf(rm1[i], __shfl_xor(rm1[i], m, 64));
            rm2[i] = fminf(rm2[i], __shfl_xor(rm2[i], m, 64));
            rm3[i] = fminf(rm3[i], __shfl_xor(rm3[i], m, 64));
        }
    }

    // ---- Publish per-row half-mins (rows: (i&3)+8*(i>>2)+4*g) ----
    if (c == 0) {                       // lanes l=0 (g=0) and l=32 (g=1)
        #pragma unroll
        for (int i = 0; i < 16; ++i) {
            const int row = (i & 3) + 8 * (i >> 2) + 4 * g;
            lmin[wid][0 * 32 + row] = rm0[i];
            lmin[wid][1 * 32 + row] = rm1[i];
            lmin[wid][2 * 32 + row] = rm2[i];
            lmin[wid][3 * 32 + row] = rm3[i];
        }
    }
    __syncthreads();

    // ---- Combine halves (wid pairs (0,2),(1,3)), clamp, block sum ----
    const int qw2  = tid >> 7;          // which strip quad
    const int idx2 = tid & 127;         // strip x row within quad
    float v = fmaxf(fminf(lmin[qw2][idx2], lmin[qw2 + 2][idx2]), 0.0f);

    #pragma unroll
    for (int off = 32; off >= 1; off >>= 1)
        v += __shfl_down(v, off, 64);

    __shared__ float wsum[4];
    if (l == 0) wsum[wid] = v;
    __syncthreads();
    if (tid == 0)
        partials[orig] = wsum[0] + wsum[1] + wsum[2] + wsum[3];
}

// ---------------- Pass 2: single-block final sum -> mean -------------------
__global__ __launch_bounds__(256) void final_kernel(
    const float* __restrict__ partials, float* __restrict__ out)
{
    const int t = (int)threadIdx.x;
    float v = partials[t] + partials[t + 256];

    #pragma unroll
    for (int off = 32; off >= 1; off >>= 1)
        v += __shfl_down(v, off, 64);

    __shared__ float wsum[4];
    const int lane = t & 63;
    const int wid  = t >> 6;
    if (lane == 0) wsum[wid] = v;
    __syncthreads();
    if (t == 0)
        out[0] = (wsum[0] + wsum[1] + wsum[2] + wsum[3]) * (1.0f / (float)NQ_TOTAL);
}

extern "C" void kernel_launch(void* const* d_in, const int* in_sizes, int n_in,
                              void* d_out, int out_size, void* d_ws, size_t ws_size,
                              hipStream_t stream) {
    const float* xyz1 = (const float*)d_in[0];
    const float* xyz2 = (const float*)d_in[1];
    float* out = (float*)d_out;
    float* partials = (float*)d_ws;   // 512 floats

    chamfer_fused_kernel<<<512, 256, 0, stream>>>(xyz1, xyz2, partials);
    final_kernel<<<1, 256, 0, stream>>>(partials, out);
}

// Round 11
// 42.558 us; speedup vs baseline: 1.1515x; 1.1515x over previous
//
#include <hip/hip_runtime.h>

// Chamfer distance via MFMA, B=16, N=M=4096, fp32 in/out. Two dispatches:
//   1) fused main: double-buffered self-pack -> mfma pair-distance ->
//      row-min -> clamp -> block partial sums
//   2) final: 1-block sum of 512 partials -> mean -> out[0]
// d(q,p) = |q|^2 - 2 q.p + |p|^2 inside mfma_f32_32x32x16_bf16 via hi/lo bf16
// splits (k0..k8: Dekker products of (-2q).p; k9,k10: |p|^2; k11,k12: |q|^2).
// R11 = verified R8 structure (2 strips/wave, 4 MFMA in flight) + pipelined
//       staging: 4 chunks x 32 tiles, issue next-chunk loads BEFORE compute,
//       pack+ds_write to the idle buffer after compute, 1 barrier per chunk.

#define BATCH 16
#define NPTS  4096
#define NQ_TOTAL (BATCH * NPTS)   // 65536 per direction

typedef __attribute__((ext_vector_type(8)))  short bf16x8;
typedef __attribute__((ext_vector_type(16))) float f32x16;
typedef __attribute__((ext_vector_type(4)))  unsigned int u32x4;

union FragCast { bf16x8 v; u32x4 u; };

__device__ __forceinline__ unsigned short bf16_rne(float v) {
    unsigned u = __float_as_uint(v);
    u += 0x7FFFu + ((u >> 16) & 1u);          // round-to-nearest-even
    return (unsigned short)(u >> 16);
}
__device__ __forceinline__ float bf16f(unsigned short h) {
    return __uint_as_float(((unsigned)h) << 16);
}

// Pack one target point into its two B-role fragment words (R6/R8 encoding).
__device__ __forceinline__ void pack_pt(float x, float y, float z,
                                        u32x4* f0u, u32x4* f1u) {
    const float S = fmaf(x, x, fmaf(y, y, z * z));
    const unsigned short Xh = bf16_rne(x), Xl = bf16_rne(x - bf16f(Xh));
    const unsigned short Yh = bf16_rne(y), Yl = bf16_rne(y - bf16f(Yh));
    const unsigned short Zh = bf16_rne(z), Zl = bf16_rne(z - bf16f(Zh));
    const unsigned short Sh = bf16_rne(S), Sl = bf16_rne(S - bf16f(Sh));
    const unsigned short one = 0x3F80;
    FragCast f0, f1;
    f0.v[0] = (short)Xh; f0.v[1] = (short)Xl; f0.v[2] = (short)Xh; f0.v[3] = (short)Yh;
    f0.v[4] = (short)Yl; f0.v[5] = (short)Yh; f0.v[6] = (short)Zh; f0.v[7] = (short)Zl;
    f1.v[0] = (short)Zh; f1.v[1] = (short)Sh; f1.v[2] = (short)Sl; f1.v[3] = (short)one;
    f1.v[4] = (short)one; f1.v[5] = 0;        f1.v[6] = 0;         f1.v[7] = 0;
    *f0u = f0.u;
    *f1u = f1.u;
}

__global__ __launch_bounds__(256, 2) void chamfer_fused_kernel(
    const float* __restrict__ xyz1, const float* __restrict__ xyz2,
    float* __restrict__ partials)
{
    // 512 blocks; XCD swizzle (512 % 8 == 0, bijective).
    const int orig = (int)blockIdx.x;
    const int wfid = (orig & 7) * 64 + (orig >> 3);
    const int og = wfid & 15;          // strip octet (8 strips)
    const int b  = (wfid >> 4) & 15;   // batch
    const int d  = wfid >> 8;          // direction

    const int tid = (int)threadIdx.x;
    const int wid = tid >> 6;
    const int l   = tid & 63;
    const int lc  = l & 31;            // lane column within 32-half
    const int g   = l >> 5;
    const int strip0 = og * 8 + wid;   // this wave's two query strips
    const int strip1 = og * 8 + wid + 4;

    const float* qpts = d ? xyz2 : xyz1;   // queries: set d
    const float* tpts = d ? xyz1 : xyz2;   // targets: set 1-d

    // ---- Build the two A-role fragments in registers (R8 encoding) ----
    const unsigned short one = 0x3F80;
    bf16x8 af0, af1;
    #pragma unroll
    for (int s = 0; s < 2; ++s) {
        const int strip = s ? strip1 : strip0;
        const int qi = b * NPTS + strip * 32 + lc;
        const float qx = qpts[qi * 3 + 0];
        const float qy = qpts[qi * 3 + 1];
        const float qz = qpts[qi * 3 + 2];
        const float mx = -2.0f * qx, my = -2.0f * qy, mz = -2.0f * qz;
        const float Q  = fmaf(qx, qx, fmaf(qy, qy, qz * qz));
        const unsigned short xh = bf16_rne(mx), xl = bf16_rne(mx - bf16f(xh));
        const unsigned short yh = bf16_rne(my), yl = bf16_rne(my - bf16f(yh));
        const unsigned short zh = bf16_rne(mz), zl = bf16_rne(mz - bf16f(zh));
        const unsigned short Qh = bf16_rne(Q),  Ql = bf16_rne(Q - bf16f(Qh));
        bf16x8 af;
        if (g == 0) {
            af[0] = (short)xh; af[1] = (short)xh; af[2] = (short)xl; af[3] = (short)yh;
            af[4] = (short)yh; af[5] = (short)yl; af[6] = (short)zh; af[7] = (short)zh;
        } else {
            af[0] = (short)zl; af[1] = (short)one; af[2] = (short)one; af[3] = (short)Qh;
            af[4] = (short)Ql; af[5] = 0;          af[6] = 0;          af[7] = 0;
        }
        if (s) af1 = af; else af0 = af;
    }

    f32x16 vzero;
    #pragma unroll
    for (int i = 0; i < 16; ++i) vzero[i] = 0.0f;

    f32x16 rm0, rm1;
    #pragma unroll
    for (int i = 0; i < 16; ++i) { rm0[i] = 1e30f; rm1[i] = 1e30f; }

    // Double-buffered staged fragments: 2 x 32 tiles x 64 lanes x 16B = 64 KiB
    __shared__ u32x4 lds[2][32 * 64];

    const float* tptr = tpts + (size_t)b * NPTS * 3;

    // ---- Prologue: stage chunk 0 into buffer 0 ----
    #pragma unroll
    for (int k = 0; k < 4; ++k) {
        const int pi = k * 256 + tid;          // 0..1023
        const float x = tptr[pi * 3 + 0];
        const float y = tptr[pi * 3 + 1];
        const float z = tptr[pi * 3 + 2];
        u32x4 f0u, f1u;
        pack_pt(x, y, z, &f0u, &f1u);
        const int t  = pi >> 5;
        const int c2 = pi & 31;
        lds[0][t * 64 + c2]      = f0u;
        lds[0][t * 64 + 32 + c2] = f1u;
    }
    __syncthreads();

    // ---- Main pipeline: 4 chunks x 32 tiles ----
    #pragma unroll
    for (int cc = 0; cc < 4; ++cc) {
        const int cur = cc & 1;

        // Issue next chunk's global loads BEFORE compute (latency hides
        // under the 16 MFMA iterations below).
        float px[4], py[4], pz[4];
        if (cc < 3) {
            #pragma unroll
            for (int k = 0; k < 4; ++k) {
                const int gp = (cc + 1) * 1024 + k * 256 + tid;
                px[k] = tptr[gp * 3 + 0];
                py[k] = tptr[gp * 3 + 1];
                pz[k] = tptr[gp * 3 + 2];
            }
        }

        // Compute this chunk: 32 tiles, 2 tiles/iter, 4 MFMA results in flight.
        #pragma unroll 2
        for (int t = 0; t < 32; t += 2) {
            FragCast ta, tb2;
            ta.u  = lds[cur][(t + 0) * 64 + l];
            tb2.u = lds[cur][(t + 1) * 64 + l];
            f32x16 a0 = __builtin_amdgcn_mfma_f32_32x32x16_bf16(af0, ta.v,  vzero, 0, 0, 0);
            f32x16 a1 = __builtin_amdgcn_mfma_f32_32x32x16_bf16(af0, tb2.v, vzero, 0, 0, 0);
            f32x16 b0 = __builtin_amdgcn_mfma_f32_32x32x16_bf16(af1, ta.v,  vzero, 0, 0, 0);
            f32x16 b1 = __builtin_amdgcn_mfma_f32_32x32x16_bf16(af1, tb2.v, vzero, 0, 0, 0);
            #pragma unroll
            for (int i = 0; i < 16; ++i) {
                rm0[i] = fminf(rm0[i], fminf(a0[i], a1[i]));   // -> v_min3_f32
                rm1[i] = fminf(rm1[i], fminf(b0[i], b1[i]));
            }
        }

        // Pack + write next chunk into the idle buffer. Safe without a
        // barrier: all waves finished READING buf[cur^1] before the barrier
        // that ended the previous iteration; compute above reads buf[cur].
        if (cc < 3) {
            #pragma unroll
            for (int k = 0; k < 4; ++k) {
                const int pi = k * 256 + tid;
                u32x4 f0u, f1u;
                pack_pt(px[k], py[k], pz[k], &f0u, &f1u);
                const int t  = pi >> 5;
                const int c2 = pi & 31;
                lds[cur ^ 1][t * 64 + c2]      = f0u;
                lds[cur ^ 1][t * 64 + 32 + c2] = f1u;
            }
        }
        __syncthreads();
    }

    // ---- Cross-lane min over the 32 columns (within each 32-lane half) ----
    #pragma unroll
    for (int m = 1; m <= 16; m <<= 1) {
        #pragma unroll
        for (int i = 0; i < 16; ++i) {
            rm0[i] = fminf(rm0[i], __shfl_xor(rm0[i], m, 64));
            rm1[i] = fminf(rm1[i], __shfl_xor(rm1[i], m, 64));
        }
    }

    // Clamp (min of clamped == clamp of min) and sum this wave's 64 rows.
    float s0 = 0.0f, s1 = 0.0f;
    #pragma unroll
    for (int i = 0; i < 16; ++i) {
        s0 += fmaxf(rm0[i], 0.0f);
        s1 += fmaxf(rm1[i], 0.0f);
    }
    s0 += __shfl_xor(s0, 32, 64);
    s1 += __shfl_xor(s1, 32, 64);
    const float s = s0 + s1;

    __shared__ float wsum[4];
    if (l == 0) wsum[wid] = s;
    __syncthreads();
    if (tid == 0)
        partials[orig] = wsum[0] + wsum[1] + wsum[2] + wsum[3];
}

// ---------------- Pass 2: single-block final sum -> mean -------------------
__global__ __launch_bounds__(256) void final_kernel(
    const float* __restrict__ partials, float* __restrict__ out)
{
    const int t = (int)threadIdx.x;
    float v = partials[t] + partials[t + 256];

    #pragma unroll
    for (int off = 32; off >= 1; off >>= 1)
        v += __shfl_down(v, off, 64);

    __shared__ float wsum[4];
    const int lane = t & 63;
    const int wid  = t >> 6;
    if (lane == 0) wsum[wid] = v;
    __syncthreads();
    if (t == 0)
        out[0] = (wsum[0] + wsum[1] + wsum[2] + wsum[3]) * (1.0f / (float)NQ_TOTAL);
}

extern "C" void kernel_launch(void* const* d_in, const int* in_sizes, int n_in,
                              void* d_out, int out_size, void* d_ws, size_t ws_size,
                              hipStream_t stream) {
    const float* xyz1 = (const float*)d_in[0];
    const float* xyz2 = (const float*)d_in[1];
    float* out = (float*)d_out;
    float* partials = (float*)d_ws;   // 512 floats

    chamfer_fused_kernel<<<512, 256, 0, stream>>>(xyz1, xyz2, partials);
    final_kernel<<<1, 256, 0, stream>>>(partials, out);
}